// Round 10
// baseline (535.214 us; speedup 1.0000x reference)
//
#include <hip/hip_runtime.h>
#include <hip/hip_bf16.h>
#include <math.h>

#define NB 2
#define SS 3072
#define CC 1536
#define NH 12
#define DH 128
#define NTOK (NB * SS)
#define WE (CC * CC)         // 2,359,296
#define LOG2E 1.4426950408889634f
#define QBLK 192             // q-rows per attn block (48 per wave, rb=3)

typedef __attribute__((ext_vector_type(8))) short short8;
typedef __attribute__((ext_vector_type(4))) float floatx4;

#define GLOAD(g, l) __builtin_amdgcn_global_load_lds( \
    (const __attribute__((address_space(1))) void*)(g), \
    (__attribute__((address_space(3))) void*)(l), 16, 0, 0)

__device__ __forceinline__ unsigned short f2bf(float f) {
    unsigned u = __float_as_uint(f);
    u += 0x7fffu + ((u >> 16) & 1u);   // RNE
    return (unsigned short)(u >> 16);
}
// XOR-swizzled chunk index in a [rows][4-chunk] LDS slab (16B chunks).
// rows r and r+8 alias (2-way, free), all else conflict-free.
__device__ __forceinline__ int swz(int row, int q) {
    return row * 4 + (q ^ ((row >> 1) & 3));
}

// ---------------------------------------------------------------------------
// Cast x (4*WE) + Wq,Wk,Wv,Wo (WE each) to one contiguous bf16 region.
// ---------------------------------------------------------------------------
__global__ __launch_bounds__(256) void cast_all(
    const float* __restrict__ x,
    const float* __restrict__ w0, const float* __restrict__ w1,
    const float* __restrict__ w2, const float* __restrict__ w3,
    unsigned short* __restrict__ o)
{
    const int y = blockIdx.y;
    const float* src = (y < 4) ? x + (size_t)y * WE
                     : (y == 4) ? w0 : (y == 5) ? w1 : (y == 6) ? w2 : w3;
    size_t i = ((size_t)blockIdx.x * 256 + threadIdx.x) * 4;
    float4 v = *(const float4*)&src[i];
    uint2 u;
    u.x = (unsigned)f2bf(v.x) | ((unsigned)f2bf(v.y) << 16);
    u.y = (unsigned)f2bf(v.z) | ((unsigned)f2bf(v.w) << 16);
    *(uint2*)&o[(size_t)y * WE + i] = u;
}

// ---------------------------------------------------------------------------
// RoPE angle table: tab[s*64+pj] = (cos, sin).
// ---------------------------------------------------------------------------
__global__ __launch_bounds__(256) void rope_table(
    const float* __restrict__ freqs, const int* __restrict__ gsz,
    float2* __restrict__ tab)
{
    const int id = blockIdx.x * 256 + threadIdx.x;   // 0..196607
    const int s = id >> 6, pj = id & 63;
    const int Hg = gsz[1], Wg = gsz[2];
    const int f = s / (Hg * Wg);
    const int rem = s - f * Hg * Wg;
    const int hh = rem / Wg;
    const int ww = rem - hh * Wg;
    const int row = (pj < 22) ? f : ((pj < 43) ? hh : ww);
    float sn, cs;
    sincosf(freqs[row * 64 + pj], &sn, &cs);
    tab[id] = make_float2(cs, sn);
}

// ---------------------------------------------------------------------------
// Fused QKV GEMM -- 256x256 tile, BK=64, 8 waves, 4-phase counted-vmcnt
// pipeline. R9 POST-MORTEM FIX (m141 precedent: sched_barrier(0) spray
// defeats the compiler scheduler, -43% measured): ALL sched_barrier(0)
// removed; m201-faithful phase form {reads+stage -> s_barrier -> setprio
// MFMA setprio -> [gate] -> s_barrier}; ds_reads rebalanced 8/4/8/4 by
// splitting phases over mf (af[0..3] then af[4..7], bf held in regs).
//   * K-tile double-buffered as four 16 KB kc-slabs -> 128 KB LDS.
//   * stages: p0 A-kc0(t+1), p1 B-kc0(t+1), p2 A-kc1(t+1), p3 B-kc1(t+1).
//   * gates (verified ledger, steady-state 4 in flight, never 0):
//     p1-end vmcnt(4) retires current kc1 pair (read in p2);
//     p3-end vmcnt(4) retires next kc0 pair (read in next p0);
//     last window p1 gate = vmcnt(0).
// Grid 24x18 = 432 blocks x 512 threads; wave (wm,wn) owns 128x64 output.
// ---------------------------------------------------------------------------
__global__ __launch_bounds__(512, 2) void qkv_gemm256(
    const unsigned short* __restrict__ X,
    const unsigned short* __restrict__ Wall,   // wqb (wq|wk|wv contiguous)
    const float* __restrict__ bq, const float* __restrict__ bk,
    const float* __restrict__ bv,
    unsigned short* __restrict__ qo, unsigned short* __restrict__ ko,
    unsigned short* __restrict__ vto)
{
    __shared__ unsigned short lds[65536];   // 128 KB = 2 buf x 4 slabs x 16 KB
    const int tid = threadIdx.x;            // 0..511
    const int w = tid >> 6, l = tid & 63;
    const int wm = w >> 2, wn = w & 3;
    const int i0 = (int)(blockIdx.x / 18) * 256;
    const int nt = (int)(blockIdx.x % 18);
    const int n0 = nt * 256;
    const int jseg = nt / 6;                // tile never straddles a weight

    const int srow0 = tid >> 2;
    const int soff0 = (((tid & 3) ^ ((srow0 >> 1) & 3))) * 8;

    // slab bases (shorts): buf*32768 + {A:0, B:16384} + kc*8192
    #define SLAB(kt, isB, kc) (lds + (((kt) & 1) ? 32768 : 0) + ((isB) ? 16384 : 0) + (kc) * 8192)

    #define STAGE_A(kt, kc) do { \
        const unsigned short* s_ = X + (size_t)(i0 + srow0) * CC + (kt) * 64 + (kc) * 32 + soff0; \
        unsigned short* d_ = SLAB(kt, 0, kc); \
        GLOAD(s_,                     d_ + (size_t)tid * 8); \
        GLOAD(s_ + (size_t)128 * CC,  d_ + (size_t)(512 + tid) * 8); \
    } while (0)

    #define STAGE_B(kt, kc) do { \
        const unsigned short* s_ = Wall + (size_t)(n0 + srow0) * CC + (kt) * 64 + (kc) * 32 + soff0; \
        unsigned short* d_ = SLAB(kt, 1, kc); \
        GLOAD(s_,                     d_ + (size_t)tid * 8); \
        GLOAD(s_ + (size_t)128 * CC,  d_ + (size_t)(512 + tid) * 8); \
    } while (0)

    floatx4 acc[8][4] = {};
    const int arow = wm * 128 + (l & 15);
    const int brow = wn * 64 + (l & 15);

    // prologue: stage tile 0's 4 slabs; wait for the kc0 pair
    STAGE_A(0, 0); STAGE_B(0, 0); STAGE_A(0, 1); STAGE_B(0, 1);
    asm volatile("s_waitcnt vmcnt(4)" ::: "memory");
    __builtin_amdgcn_s_barrier();

    for (int tt = 0; tt < 24; ++tt) {
        short8 af[4], bf[4];

        // ---- phase 0: kc0, mf 0..3 x all nf (8 reads); stage A-kc0(t+1) ----
        {
            const unsigned short* As = SLAB(tt, 0, 0);
            const unsigned short* Bs = SLAB(tt, 1, 0);
            #pragma unroll
            for (int mf = 0; mf < 4; ++mf)
                af[mf] = *(const short8*)&As[(size_t)swz(arow + mf * 16, l >> 4) * 8];
            #pragma unroll
            for (int nf = 0; nf < 4; ++nf)
                bf[nf] = *(const short8*)&Bs[(size_t)swz(brow + nf * 16, l >> 4) * 8];
            if (tt + 1 < 24) STAGE_A(tt + 1, 0);
            __builtin_amdgcn_s_barrier();
            __builtin_amdgcn_s_setprio(1);
            #pragma unroll
            for (int mf = 0; mf < 4; ++mf)
                #pragma unroll
                for (int nf = 0; nf < 4; ++nf)
                    acc[mf][nf] = __builtin_amdgcn_mfma_f32_16x16x32_bf16(
                        af[mf], bf[nf], acc[mf][nf], 0, 0, 0);
            __builtin_amdgcn_s_setprio(0);
            __builtin_amdgcn_s_barrier();
        }

        // ---- phase 1: kc0, mf 4..7 (4 reads, bf held); stage B-kc0(t+1); GATE ----
        {
            const unsigned short* As = SLAB(tt, 0, 0);
            #pragma unroll
            for (int mf = 0; mf < 4; ++mf)
                af[mf] = *(const short8*)&As[(size_t)swz(arow + (mf + 4) * 16, l >> 4) * 8];
            if (tt + 1 < 24) STAGE_B(tt + 1, 0);
            __builtin_amdgcn_s_barrier();
            __builtin_amdgcn_s_setprio(1);
            #pragma unroll
            for (int mf = 0; mf < 4; ++mf)
                #pragma unroll
                for (int nf = 0; nf < 4; ++nf)
                    acc[mf + 4][nf] = __builtin_amdgcn_mfma_f32_16x16x32_bf16(
                        af[mf], bf[nf], acc[mf + 4][nf], 0, 0, 0);
            __builtin_amdgcn_s_setprio(0);
            if (tt + 1 < 24) { asm volatile("s_waitcnt vmcnt(4)" ::: "memory"); }
            else             { asm volatile("s_waitcnt vmcnt(0)" ::: "memory"); }
            __builtin_amdgcn_s_barrier();
        }

        // ---- phase 2: kc1, mf 0..3 (8 reads); stage A-kc1(t+1) ----
        {
            const unsigned short* As = SLAB(tt, 0, 1);
            const unsigned short* Bs = SLAB(tt, 1, 1);
            #pragma unroll
            for (int mf = 0; mf < 4; ++mf)
                af[mf] = *(const short8*)&As[(size_t)swz(arow + mf * 16, l >> 4) * 8];
            #pragma unroll
            for (int nf = 0; nf < 4; ++nf)
                bf[nf] = *(const short8*)&Bs[(size_t)swz(brow + nf * 16, l >> 4) * 8];
            if (tt + 1 < 24) STAGE_A(tt + 1, 1);
            __builtin_amdgcn_s_barrier();
            __builtin_amdgcn_s_setprio(1);
            #pragma unroll
            for (int mf = 0; mf < 4; ++mf)
                #pragma unroll
                for (int nf = 0; nf < 4; ++nf)
                    acc[mf][nf] = __builtin_amdgcn_mfma_f32_16x16x32_bf16(
                        af[mf], bf[nf], acc[mf][nf], 0, 0, 0);
            __builtin_amdgcn_s_setprio(0);
            __builtin_amdgcn_s_barrier();
        }

        // ---- phase 3: kc1, mf 4..7 (4 reads); stage B-kc1(t+1); GATE ----
        {
            const unsigned short* As = SLAB(tt, 0, 1);
            #pragma unroll
            for (int mf = 0; mf < 4; ++mf)
                af[mf] = *(const short8*)&As[(size_t)swz(arow + (mf + 4) * 16, l >> 4) * 8];
            if (tt + 1 < 24) STAGE_B(tt + 1, 1);
            __builtin_amdgcn_s_barrier();
            __builtin_amdgcn_s_setprio(1);
            #pragma unroll
            for (int mf = 0; mf < 4; ++mf)
                #pragma unroll
                for (int nf = 0; nf < 4; ++nf)
                    acc[mf + 4][nf] = __builtin_amdgcn_mfma_f32_16x16x32_bf16(
                        af[mf], bf[nf], acc[mf + 4][nf], 0, 0, 0);
            __builtin_amdgcn_s_setprio(0);
            if (tt + 1 < 24) { asm volatile("s_waitcnt vmcnt(4)" ::: "memory"); }
            __builtin_amdgcn_s_barrier();
        }
    }

    // ---- epilogue ----
    const float* bias = (jseg == 0) ? bq : (jseg == 1) ? bk : bv;
    unsigned short* Y  = (jseg == 0) ? qo : (jseg == 1) ? ko : vto;
    #pragma unroll
    for (int mf = 0; mf < 8; ++mf)
        #pragma unroll
        for (int nf = 0; nf < 4; ++nf) {
            const int ng = n0 + wn * 64 + nf * 16 + (l & 15);
            const int np = ng - jseg * 1536;
            const float bv2 = bias[np];
            const int h = np >> 7, td = np & 127;
            #pragma unroll
            for (int r = 0; r < 4; ++r) {
                const int m = i0 + wm * 128 + mf * 16 + (l >> 4) * 4 + r;
                const float val = acc[mf][nf][r] + bv2;
                const int b = (m >= SS) ? 1 : 0;
                const int s = m - b * SS;
                if (jseg < 2)
                    Y[((size_t)(b * NH + h) * SS + s) * DH + td] = f2bf(val);
                else
                    Y[((size_t)(b * NH + h) * DH + td) * SS + s] = f2bf(val);
            }
        }
    #undef SLAB
    #undef STAGE_A
    #undef STAGE_B
}

// ---------------------------------------------------------------------------
// O-projection (swizzled LDS, two-barrier loop): fp32 out = A @ Wo^T + bo.
// ---------------------------------------------------------------------------
__global__ __launch_bounds__(256) void gemm_o(
    const unsigned short* __restrict__ X, const unsigned short* __restrict__ Wt,
    const float* __restrict__ bias, float* __restrict__ Y)
{
    __shared__ unsigned short As[128 * 32];
    __shared__ unsigned short Bs[128 * 32];
    const int tid = threadIdx.x;
    const int w = tid >> 6, l = tid & 63;
    const int i0 = blockIdx.x * 128, j0 = blockIdx.y * 128;
    const int srow = tid >> 2;
    const int gk8 = (((tid & 3) ^ ((srow >> 1) & 3))) * 8;

    floatx4 acc[4][4] = {};
    for (int k0 = 0; k0 < CC; k0 += 32) {
        __syncthreads();
        GLOAD(X + (size_t)(i0 + srow) * CC + k0 + gk8,        As + (size_t)tid * 8);
        GLOAD(X + (size_t)(i0 + 64 + srow) * CC + k0 + gk8,   As + (size_t)(256 + tid) * 8);
        GLOAD(Wt + (size_t)(j0 + srow) * CC + k0 + gk8,       Bs + (size_t)tid * 8);
        GLOAD(Wt + (size_t)(j0 + 64 + srow) * CC + k0 + gk8,  Bs + (size_t)(256 + tid) * 8);
        __syncthreads();
        const int wr = (w >> 1) * 64, wc = (w & 1) * 64;
        short8 af[4], bf[4];
        #pragma unroll
        for (int mb = 0; mb < 4; ++mb)
            af[mb] = *(const short8*)&As[swz(wr + mb * 16 + (l & 15), l >> 4) * 8];
        #pragma unroll
        for (int nb = 0; nb < 4; ++nb)
            bf[nb] = *(const short8*)&Bs[swz(wc + nb * 16 + (l & 15), l >> 4) * 8];
        #pragma unroll
        for (int mb = 0; mb < 4; ++mb)
            #pragma unroll
            for (int nb = 0; nb < 4; ++nb)
                acc[mb][nb] = __builtin_amdgcn_mfma_f32_16x16x32_bf16(
                    af[mb], bf[nb], acc[mb][nb], 0, 0, 0);
    }

    const int wr = (w >> 1) * 64, wc = (w & 1) * 64;
    #pragma unroll
    for (int mb = 0; mb < 4; ++mb)
        #pragma unroll
        for (int nb = 0; nb < 4; ++nb) {
            const int n = j0 + wc + nb * 16 + (l & 15);
            const float bv = bias[n];
            #pragma unroll
            for (int r = 0; r < 4; ++r) {
                const int m = i0 + wr + mb * 16 + (l >> 4) * 4 + r;
                Y[(size_t)m * CC + n] = acc[mb][nb][r] + bv;
            }
        }
}

// ---------------------------------------------------------------------------
// Fused RMSNorm + RoPE (table-driven), in-place bf16 (B,NH,S,DH).
// ---------------------------------------------------------------------------
__global__ __launch_bounds__(256) void norm_rope(
    unsigned short* __restrict__ qb, unsigned short* __restrict__ kb,
    const float* __restrict__ nqw, const float* __restrict__ nkw,
    const float2* __restrict__ tab)
{
    const int bid = blockIdx.x;
    const int which = (bid >= NTOK) ? 1 : 0;
    const int tok = bid - which * NTOK;
    unsigned short* t    = which ? kb : qb;
    const float* wgt     = which ? nkw : nqw;
    const float outscale = which ? 1.0f : 0.08838834764831845f * LOG2E;
    const int b = tok / SS, s = tok - b * SS;
    const int tid = threadIdx.x;

    float2 vals[3];
    size_t addrs[3];
    float ss = 0.f;
    #pragma unroll
    for (int kt = 0; kt < 3; ++kt) {
        int p = tid + kt * 256;
        int h = p >> 6, pj = p & 63;
        size_t addr = ((size_t)(b * NH + h) * SS + s) * DH + 2 * pj;
        addrs[kt] = addr;
        unsigned u = *(const unsigned*)&t[addr];
        float2 v;
        v.x = __uint_as_float(u << 16);
        v.y = __uint_as_float(u & 0xffff0000u);
        vals[kt] = v;
        ss += v.x * v.x + v.y * v.y;
    }
    #pragma unroll
    for (int off = 32; off > 0; off >>= 1) ss += __shfl_down(ss, off, 64);
    __shared__ float red[4];
    if ((tid & 63) == 0) red[tid >> 6] = ss;
    __syncthreads();
    const float total = red[0] + red[1] + red[2] + red[3];
    const float rstd = rsqrtf(total * (1.0f / CC) + 1e-6f) * outscale;

    #pragma unroll
    for (int kt = 0; kt < 3; ++kt) {
        int p = tid + kt * 256;
        int h = p >> 6, pj = p & 63;
        float2 cssn = tab[s * 64 + pj];
        int ch = h * DH + 2 * pj;
        float te = vals[kt].x * rstd * wgt[ch];
        float to = vals[kt].y * rstd * wgt[ch + 1];
        unsigned o = (unsigned)f2bf(te * cssn.x - to * cssn.y) |
                     ((unsigned)f2bf(te * cssn.y + to * cssn.x) << 16);
        *(unsigned*)&t[addrs[kt]] = o;
    }
}

// ---------------------------------------------------------------------------
// MFMA flash attention -- rb=3 / QBLK=192 (R7-verified form, unchanged).
// ---------------------------------------------------------------------------
__global__ __launch_bounds__(256, 2) void flash_attn_mfma(
    const unsigned short* __restrict__ qg, const unsigned short* __restrict__ kg,
    const unsigned short* __restrict__ vg, const int* __restrict__ seq_lens,
    unsigned short* __restrict__ out)
{
    __shared__ unsigned short lds[32768];    // 64 KB: KV double buffer
    const int tid = threadIdx.x;
    const int w = tid >> 6, l = tid & 63;
    const int g4 = (l >> 4) * 4;             // key base of this lane group

    const int bid = blockIdx.x;
    const int qt = bid / (NB * NH);          // 0..15
    const int rem0 = bid - qt * (NB * NH);
    const int h = rem0 >> 1;
    const int b = rem0 & 1;
    const int slen = seq_lens[b];
    const int s0 = qt * QBLK;

    const unsigned short* qbase = qg + ((size_t)(b * NH + h) * SS + s0) * DH;
    const unsigned short* kbase = kg + ((size_t)(b * NH + h) * SS) * DH;
    const unsigned short* vbase = vg + ((size_t)(b * NH + h) * DH) * SS;

    // ---- stage Q (192x128 = 48 KB) through LDS, pull frags to regs ----
    #pragma unroll
    for (int i = 0; i < 12; ++i) {
        int kc = i / 3;
        int r2 = (i % 3) * 256 + tid;        // chunk within kc-slab
        int row = r2 >> 2, sq = r2 & 3;
        GLOAD(qbase + (size_t)row * DH + kc * 32 + (sq ^ ((row >> 1) & 3)) * 8,
              lds + (size_t)(kc * 768 + r2) * 8);
    }
    __syncthreads();
    short8 qf[3][4];
    #pragma unroll
    for (int rb = 0; rb < 3; ++rb)
        #pragma unroll
        for (int kc = 0; kc < 4; ++kc)
            qf[rb][kc] = *(const short8*)&lds[(kc * 768 + swz(w * 48 + rb * 16 + (l & 15), l >> 4)) * 8];
    __syncthreads();   // all waves' Q-frag reads done before region overwrite

    // per-thread chunk descriptors for K/V staging (KVBLK=64)
    int ksrc[4], vsrc[4];
    #pragma unroll
    for (int i = 0; i < 4; ++i) {
        int cid = i * 256 + tid;
        {   int kc = cid >> 8, r2 = cid & 255, row = r2 >> 2, sq = r2 & 3;
            ksrc[i] = row * DH + kc * 32 + (sq ^ ((row >> 1) & 3)) * 8; }
        {   int ks = cid >> 9, r2 = cid & 511, dc = r2 >> 2, sq = r2 & 3;
            vsrc[i] = dc * SS + ks * 32 + (sq ^ ((dc >> 1) & 3)) * 8; }
    }

    const int ntiles = (slen + 63) >> 6;

    // prologue: GLOAD tile 0 -> buf0 (K at 0, V at +8192 shorts)
    #pragma unroll
    for (int i = 0; i < 4; ++i) {
        int cid = i * 256 + tid;
        GLOAD(kbase + ksrc[i],        lds + (size_t)cid * 8);
        GLOAD(vbase + vsrc[i],        lds + 8192 + (size_t)cid * 8);
    }

    floatx4 acc[3][8] = {};
    float lsum[3] = {};                 // per-lane: q = l&15 of block rb

    for (int kt = 0; kt < ntiles; ++kt) {
        __syncthreads();   // drains tile kt's GLOADs (issued a phase ago)

        if (kt + 1 < ntiles) {   // prefetch tile kt+1 into other buffer
            const unsigned short* kb2 = kbase + (size_t)(kt + 1) * 64 * DH;
            const unsigned short* vb2 = vbase + (size_t)(kt + 1) * 64;
            unsigned short* dst = lds + ((kt + 1) & 1) * 16384;
            #pragma unroll
            for (int i = 0; i < 4; ++i) {
                int cid = i * 256 + tid;
                GLOAD(kb2 + ksrc[i], dst + (size_t)cid * 8);
                GLOAD(vb2 + vsrc[i], dst + 8192 + (size_t)cid * 8);
            }
        }

        const unsigned short* Ks = lds + (kt & 1) * 16384;
        const unsigned short* Vs = Ks + 8192;

        // S^T = K Q^T (swapped): lane holds q=l&15, keys {g4+r + 16*nb};
        // K frags shared across all 3 rb -> 16 reads serve 48 MFMA.
        floatx4 sv[3][4] = {};
        __builtin_amdgcn_s_setprio(1);
        #pragma unroll
        for (int kc = 0; kc < 4; ++kc) {
            short8 kf[4];
            #pragma unroll
            for (int nb = 0; nb < 4; ++nb)
                kf[nb] = *(const short8*)&Ks[(kc * 256 + swz(nb * 16 + (l & 15), l >> 4)) * 8];
            #pragma unroll
            for (int rb = 0; rb < 3; ++rb)
                #pragma unroll
                for (int nb = 0; nb < 4; ++nb)
                    sv[rb][nb] = __builtin_amdgcn_mfma_f32_16x16x32_bf16(
                        kf[nb], qf[rb][kc], sv[rb][nb], 0, 0, 0);
        }
        __builtin_amdgcn_s_setprio(0);

        // softmax (no max-subtraction) + in-register P redistribution
        const int valid = slen - kt * 64;
        short8 pa[3][2];
        #pragma unroll
        for (int rb = 0; rb < 3; ++rb) {
            if (valid >= 64) {
                #pragma unroll
                for (int nb = 0; nb < 4; ++nb)
                    #pragma unroll
                    for (int r = 0; r < 4; ++r)
                        sv[rb][nb][r] = exp2f(sv[rb][nb][r]);
            } else {
                #pragma unroll
                for (int nb = 0; nb < 4; ++nb)
                    #pragma unroll
                    for (int r = 0; r < 4; ++r) {
                        const int key = g4 + r + 16 * nb;
                        sv[rb][nb][r] = (key < valid) ? exp2f(sv[rb][nb][r]) : 0.0f;
                    }
            }
            #pragma unroll
            for (int nb = 0; nb < 4; ++nb)
                lsum[rb] += (sv[rb][nb][0] + sv[rb][nb][1]) +
                            (sv[rb][nb][2] + sv[rb][nb][3]);

            unsigned dw0[4], dw1[4];
            #pragma unroll
            for (int nb = 0; nb < 4; ++nb) {
                union { __hip_bfloat162 v; unsigned u; } c0, c1;
                c0.v = __float22bfloat162_rn(make_float2(sv[rb][nb][0], sv[rb][nb][1]));
                c1.v = __float22bfloat162_rn(make_float2(sv[rb][nb][2], sv[rb][nb][3]));
                dw0[nb] = c0.u;
                dw1[nb] = c1.u;
            }
            // permlane redistribution -> A-frag: lane needs keys 8g..8g+7
            #pragma unroll
            for (int ks = 0; ks < 2; ++ks) {
                unsigned x0 = dw0[2 * ks], y0 = dw0[2 * ks + 1];
                unsigned x1 = dw1[2 * ks], y1 = dw1[2 * ks + 1];
                asm("v_permlane32_swap_b32 %0, %1" : "+v"(x0), "+v"(y0));
                asm("v_permlane16_swap_b32 %0, %1" : "+v"(x0), "+v"(y0));
                asm("v_permlane32_swap_b32 %0, %1" : "+v"(x1), "+v"(y1));
                asm("v_permlane16_swap_b32 %0, %1" : "+v"(x1), "+v"(y1));
                union { short8 s; unsigned u[4]; } pk;
                pk.u[0] = x0; pk.u[1] = x1; pk.u[2] = y0; pk.u[3] = y1;
                pa[rb][ks] = pk.s;
            }
        }

        // O += P V : V frags shared across all 3 rb -> 16 reads, 48 MFMA
        __builtin_amdgcn_s_setprio(1);
        #pragma unroll
        for (int ks = 0; ks < 2; ++ks)
            #pragma unroll
            for (int nb2 = 0; nb2 < 8; ++nb2) {
                short8 vf = *(const short8*)&Vs[(ks * 512 + swz(nb2 * 16 + (l & 15), l >> 4)) * 8];
                #pragma unroll
                for (int rb = 0; rb < 3; ++rb)
                    acc[rb][nb2] = __builtin_amdgcn_mfma_f32_16x16x32_bf16(
                        pa[rb][ks], vf, acc[rb][nb2], 0, 0, 0);
            }
        __builtin_amdgcn_s_setprio(0);
    }

    #pragma unroll
    for (int rb = 0; rb < 3; ++rb) {
        float s = lsum[rb];
        s += __shfl_xor(s, 16, 64);
        s += __shfl_xor(s, 32, 64);
        float rl[4];
        #pragma unroll
        for (int r = 0; r < 4; ++r)
            rl[r] = 1.0f / __shfl(s, g4 + r, 64);
        #pragma unroll
        for (int nb2 = 0; nb2 < 8; ++nb2) {
            const int col = h * DH + nb2 * 16 + (l & 15);
            #pragma unroll
            for (int r = 0; r < 4; ++r) {
                const int srow = s0 + w * 48 + rb * 16 + (l >> 4) * 4 + r;
                out[((size_t)b * SS + srow) * CC + col] = f2bf(acc[rb][nb2][r] * rl[r]);
            }
        }
    }
}

// ---------------------------------------------------------------------------
extern "C" void kernel_launch(void* const* d_in, const int* in_sizes, int n_in,
                              void* d_out, int out_size, void* d_ws, size_t ws_size,
                              hipStream_t stream) {
    const float* x          = (const float*)d_in[0];
    const int*   seq_lens   = (const int*)d_in[1];
    const int*   grid_sizes = (const int*)d_in[2];
    const float* freqs      = (const float*)d_in[3];
    const float* Wq         = (const float*)d_in[4];
    const float* bq         = (const float*)d_in[5];
    const float* Wk         = (const float*)d_in[6];
    const float* bk         = (const float*)d_in[7];
    const float* Wv         = (const float*)d_in[8];
    const float* bv         = (const float*)d_in[9];
    const float* Wo         = (const float*)d_in[10];
    const float* bo         = (const float*)d_in[11];
    const float* nqw        = (const float*)d_in[12];
    const float* nkw        = (const float*)d_in[13];
    float* out = (float*)d_out;

    const size_t TE = (size_t)NTOK * CC;   // 9,437,184 (= 4*WE)
    unsigned short* xb  = (unsigned short*)d_ws;   // xb..wob contiguous
    unsigned short* wqb = xb + TE;
    unsigned short* wkb = wqb + WE;
    unsigned short* wvb = wkb + WE;
    unsigned short* wob = wvb + WE;
    unsigned short* qb  = wob + WE;
    unsigned short* kb  = qb + TE;
    unsigned short* vtb = kb + TE;
    unsigned short* ab  = vtb + TE;
    float2* tab = (float2*)(ab + TE);      // 3072*64 float2 = 1.5 MB

    cast_all<<<dim3(WE / 1024, 8), 256, 0, stream>>>(x, Wq, Wk, Wv, Wo, xb);
    rope_table<<<dim3(SS * 64 / 256), 256, 0, stream>>>(freqs, grid_sizes, tab);

    qkv_gemm256<<<dim3(24 * 18), 512, 0, stream>>>(
        xb, wqb, bq, bk, bv, qb, kb, vtb);

    norm_rope<<<dim3(2 * NTOK), 256, 0, stream>>>(qb, kb, nqw, nkw, tab);

    flash_attn_mfma<<<dim3(NB * NH * (SS / QBLK)), 256, 0, stream>>>(qb, kb, vtb, seq_lens, ab);

    gemm_o<<<dim3(NTOK / 128, CC / 128), 256, 0, stream>>>(ab, wob, bo, out);
}

// Round 11
// 487.780 us; speedup vs baseline: 1.0972x; 1.0972x over previous
//
#include <hip/hip_runtime.h>
#include <hip/hip_bf16.h>
#include <math.h>

#define NB 2
#define SS 3072
#define CC 1536
#define NH 12
#define DH 128
#define NTOK (NB * SS)
#define WE (CC * CC)         // 2,359,296
#define LOG2E 1.4426950408889634f
#define QBLK 192             // q-rows per attn block (48 per wave, rb=3)

typedef __attribute__((ext_vector_type(8))) short short8;
typedef __attribute__((ext_vector_type(4))) float floatx4;

#define GLOAD(g, l) __builtin_amdgcn_global_load_lds( \
    (const __attribute__((address_space(1))) void*)(g), \
    (__attribute__((address_space(3))) void*)(l), 16, 0, 0)

__device__ __forceinline__ unsigned short f2bf(float f) {
    unsigned u = __float_as_uint(f);
    u += 0x7fffu + ((u >> 16) & 1u);   // RNE
    return (unsigned short)(u >> 16);
}
// XOR-swizzled chunk index in a [rows][4-chunk] LDS slab (16B chunks).
// rows r and r+8 alias (2-way, free), all else conflict-free.
__device__ __forceinline__ int swz(int row, int q) {
    return row * 4 + (q ^ ((row >> 1) & 3));
}

// ---------------------------------------------------------------------------
// Fused: cast x + 4 weights to bf16 (y=0..7) AND build RoPE table (y=8).
// One launch instead of two.
// ---------------------------------------------------------------------------
__global__ __launch_bounds__(256) void cast_rope(
    const float* __restrict__ x,
    const float* __restrict__ w0, const float* __restrict__ w1,
    const float* __restrict__ w2, const float* __restrict__ w3,
    unsigned short* __restrict__ o,
    const float* __restrict__ freqs, const int* __restrict__ gsz,
    float2* __restrict__ tab)
{
    const int y = blockIdx.y;
    if (y == 8) {                       // RoPE table slice
        const int id = blockIdx.x * 256 + threadIdx.x;
        if (id >= SS * 64) return;      // only first 768 x-blocks active
        const int s = id >> 6, pj = id & 63;
        const int Hg = gsz[1], Wg = gsz[2];
        const int f = s / (Hg * Wg);
        const int rem = s - f * Hg * Wg;
        const int hh = rem / Wg;
        const int ww = rem - hh * Wg;
        const int row = (pj < 22) ? f : ((pj < 43) ? hh : ww);
        float sn, cs;
        sincosf(freqs[row * 64 + pj], &sn, &cs);
        tab[id] = make_float2(cs, sn);
        return;
    }
    const float* src = (y < 4) ? x + (size_t)y * WE
                     : (y == 4) ? w0 : (y == 5) ? w1 : (y == 6) ? w2 : w3;
    size_t i = ((size_t)blockIdx.x * 256 + threadIdx.x) * 4;
    float4 v = *(const float4*)&src[i];
    uint2 u;
    u.x = (unsigned)f2bf(v.x) | ((unsigned)f2bf(v.y) << 16);
    u.y = (unsigned)f2bf(v.z) | ((unsigned)f2bf(v.w) << 16);
    *(uint2*)&o[(size_t)y * WE + i] = u;
}

// ---------------------------------------------------------------------------
// Fused QKV GEMM (swizzled LDS, two-barrier loop -- R7-verified form).
// jseg 0,1 -> bf16 (B,NH,S,DH); 2 -> (B,NH,DH,S).
// ---------------------------------------------------------------------------
__global__ __launch_bounds__(256) void qkv_gemm(
    const unsigned short* __restrict__ X,
    const unsigned short* __restrict__ Wqb, const unsigned short* __restrict__ Wkb,
    const unsigned short* __restrict__ Wvb,
    const float* __restrict__ bq, const float* __restrict__ bk,
    const float* __restrict__ bv,
    unsigned short* __restrict__ qo, unsigned short* __restrict__ ko,
    unsigned short* __restrict__ vto)
{
    __shared__ unsigned short As[128 * 32];
    __shared__ unsigned short Bs[128 * 32];
    const int tid = threadIdx.x;
    const int w = tid >> 6, l = tid & 63;
    const int jseg = blockIdx.y / 12;
    const unsigned short* Wt = (jseg == 0) ? Wqb : (jseg == 1) ? Wkb : Wvb;
    const float* bias        = (jseg == 0) ? bq  : (jseg == 1) ? bk  : bv;
    unsigned short* Y        = (jseg == 0) ? qo  : (jseg == 1) ? ko  : vto;
    const int i0 = blockIdx.x * 128, j0 = (blockIdx.y % 12) * 128;
    const int srow = tid >> 2;
    const int gk8 = (((tid & 3) ^ ((srow >> 1) & 3))) * 8;   // swizzled global chunk

    floatx4 acc[4][4] = {};
    for (int k0 = 0; k0 < CC; k0 += 32) {
        __syncthreads();
        GLOAD(X + (size_t)(i0 + srow) * CC + k0 + gk8,        As + (size_t)tid * 8);
        GLOAD(X + (size_t)(i0 + 64 + srow) * CC + k0 + gk8,   As + (size_t)(256 + tid) * 8);
        GLOAD(Wt + (size_t)(j0 + srow) * CC + k0 + gk8,       Bs + (size_t)tid * 8);
        GLOAD(Wt + (size_t)(j0 + 64 + srow) * CC + k0 + gk8,  Bs + (size_t)(256 + tid) * 8);
        __syncthreads();
        const int wr = (w >> 1) * 64, wc = (w & 1) * 64;
        short8 af[4], bf[4];
        #pragma unroll
        for (int mb = 0; mb < 4; ++mb)
            af[mb] = *(const short8*)&As[swz(wr + mb * 16 + (l & 15), l >> 4) * 8];
        #pragma unroll
        for (int nb = 0; nb < 4; ++nb)
            bf[nb] = *(const short8*)&Bs[swz(wc + nb * 16 + (l & 15), l >> 4) * 8];
        #pragma unroll
        for (int mb = 0; mb < 4; ++mb)
            #pragma unroll
            for (int nb = 0; nb < 4; ++nb)
                acc[mb][nb] = __builtin_amdgcn_mfma_f32_16x16x32_bf16(
                    af[mb], bf[nb], acc[mb][nb], 0, 0, 0);
    }

    const int wr = (w >> 1) * 64, wc = (w & 1) * 64;
    #pragma unroll
    for (int mb = 0; mb < 4; ++mb)
        #pragma unroll
        for (int nb = 0; nb < 4; ++nb) {
            const int n = j0 + wc + nb * 16 + (l & 15);
            const float bv2 = bias[n];
            const int h = n >> 7, td = n & 127;
            #pragma unroll
            for (int r = 0; r < 4; ++r) {
                const int m = i0 + wr + mb * 16 + (l >> 4) * 4 + r;
                const float val = acc[mb][nb][r] + bv2;
                const int b = (m >= SS) ? 1 : 0;
                const int s = m - b * SS;
                if (jseg < 2)
                    Y[((size_t)(b * NH + h) * SS + s) * DH + td] = f2bf(val);
                else
                    Y[((size_t)(b * NH + h) * DH + td) * SS + s] = f2bf(val);
            }
        }
}

// ---------------------------------------------------------------------------
// O-projection (swizzled LDS, two-barrier loop): fp32 out = A @ Wo^T + bo.
// ---------------------------------------------------------------------------
__global__ __launch_bounds__(256) void gemm_o(
    const unsigned short* __restrict__ X, const unsigned short* __restrict__ Wt,
    const float* __restrict__ bias, float* __restrict__ Y)
{
    __shared__ unsigned short As[128 * 32];
    __shared__ unsigned short Bs[128 * 32];
    const int tid = threadIdx.x;
    const int w = tid >> 6, l = tid & 63;
    const int i0 = blockIdx.x * 128, j0 = blockIdx.y * 128;
    const int srow = tid >> 2;
    const int gk8 = (((tid & 3) ^ ((srow >> 1) & 3))) * 8;

    floatx4 acc[4][4] = {};
    for (int k0 = 0; k0 < CC; k0 += 32) {
        __syncthreads();
        GLOAD(X + (size_t)(i0 + srow) * CC + k0 + gk8,        As + (size_t)tid * 8);
        GLOAD(X + (size_t)(i0 + 64 + srow) * CC + k0 + gk8,   As + (size_t)(256 + tid) * 8);
        GLOAD(Wt + (size_t)(j0 + srow) * CC + k0 + gk8,       Bs + (size_t)tid * 8);
        GLOAD(Wt + (size_t)(j0 + 64 + srow) * CC + k0 + gk8,  Bs + (size_t)(256 + tid) * 8);
        __syncthreads();
        const int wr = (w >> 1) * 64, wc = (w & 1) * 64;
        short8 af[4], bf[4];
        #pragma unroll
        for (int mb = 0; mb < 4; ++mb)
            af[mb] = *(const short8*)&As[swz(wr + mb * 16 + (l & 15), l >> 4) * 8];
        #pragma unroll
        for (int nb = 0; nb < 4; ++nb)
            bf[nb] = *(const short8*)&Bs[swz(wc + nb * 16 + (l & 15), l >> 4) * 8];
        #pragma unroll
        for (int mb = 0; mb < 4; ++mb)
            #pragma unroll
            for (int nb = 0; nb < 4; ++nb)
                acc[mb][nb] = __builtin_amdgcn_mfma_f32_16x16x32_bf16(
                    af[mb], bf[nb], acc[mb][nb], 0, 0, 0);
    }

    const int wr = (w >> 1) * 64, wc = (w & 1) * 64;
    #pragma unroll
    for (int mb = 0; mb < 4; ++mb)
        #pragma unroll
        for (int nb = 0; nb < 4; ++nb) {
            const int n = j0 + wc + nb * 16 + (l & 15);
            const float bv = bias[n];
            #pragma unroll
            for (int r = 0; r < 4; ++r) {
                const int m = i0 + wr + mb * 16 + (l >> 4) * 4 + r;
                Y[(size_t)m * CC + n] = acc[mb][nb][r] + bv;
            }
        }
}

// ---------------------------------------------------------------------------
// Fused RMSNorm + RoPE, MERGED q+k per token (half the blocks; the cos/sin
// table loads and index math are shared between the q and k of one token).
// In-place bf16 (B,NH,S,DH). Math identical to the split version.
// ---------------------------------------------------------------------------
__global__ __launch_bounds__(256) void norm_rope(
    unsigned short* __restrict__ qb, unsigned short* __restrict__ kb,
    const float* __restrict__ nqw, const float* __restrict__ nkw,
    const float2* __restrict__ tab)
{
    const int tok = blockIdx.x;          // 0..NTOK-1
    const int b = tok / SS, s = tok - b * SS;
    const int tid = threadIdx.x;
    const float qscale = 0.08838834764831845f * LOG2E;

    float2 qv[3], kv[3];
    size_t addrs[3];
    float ssq = 0.f, ssk = 0.f;
    #pragma unroll
    for (int kt = 0; kt < 3; ++kt) {
        int p = tid + kt * 256;
        int h = p >> 6, pj = p & 63;
        size_t addr = ((size_t)(b * NH + h) * SS + s) * DH + 2 * pj;
        addrs[kt] = addr;
        unsigned uq = *(const unsigned*)&qb[addr];
        unsigned uk = *(const unsigned*)&kb[addr];
        float2 vq, vk;
        vq.x = __uint_as_float(uq << 16);
        vq.y = __uint_as_float(uq & 0xffff0000u);
        vk.x = __uint_as_float(uk << 16);
        vk.y = __uint_as_float(uk & 0xffff0000u);
        qv[kt] = vq; kv[kt] = vk;
        ssq += vq.x * vq.x + vq.y * vq.y;
        ssk += vk.x * vk.x + vk.y * vk.y;
    }
    #pragma unroll
    for (int off = 32; off > 0; off >>= 1) {
        ssq += __shfl_down(ssq, off, 64);
        ssk += __shfl_down(ssk, off, 64);
    }
    __shared__ float redq[4], redk[4];
    if ((tid & 63) == 0) { redq[tid >> 6] = ssq; redk[tid >> 6] = ssk; }
    __syncthreads();
    const float rq = rsqrtf((redq[0] + redq[1] + redq[2] + redq[3]) * (1.0f / CC) + 1e-6f) * qscale;
    const float rk = rsqrtf((redk[0] + redk[1] + redk[2] + redk[3]) * (1.0f / CC) + 1e-6f);

    #pragma unroll
    for (int kt = 0; kt < 3; ++kt) {
        int p = tid + kt * 256;
        int h = p >> 6, pj = p & 63;
        float2 cssn = tab[s * 64 + pj];
        int ch = h * DH + 2 * pj;
        {
            float te = qv[kt].x * rq * nqw[ch];
            float to = qv[kt].y * rq * nqw[ch + 1];
            unsigned o = (unsigned)f2bf(te * cssn.x - to * cssn.y) |
                         ((unsigned)f2bf(te * cssn.y + to * cssn.x) << 16);
            *(unsigned*)&qb[addrs[kt]] = o;
        }
        {
            float te = kv[kt].x * rk * nkw[ch];
            float to = kv[kt].y * rk * nkw[ch + 1];
            unsigned o = (unsigned)f2bf(te * cssn.x - to * cssn.y) |
                         ((unsigned)f2bf(te * cssn.y + to * cssn.x) << 16);
            *(unsigned*)&kb[addrs[kt]] = o;
        }
    }
}

// ---------------------------------------------------------------------------
// MFMA flash attention -- rb=3 / QBLK=192 (R7-verified structure) with the
// last KV tile PEELED out of the main loop: iterations 0..ntiles-2 are
// guaranteed full (no mask branch/compares); the tail tile handles the
// rem<64 mask once. Prefetch pointers strength-reduced to running adds.
// ---------------------------------------------------------------------------
__global__ __launch_bounds__(256, 2) void flash_attn_mfma(
    const unsigned short* __restrict__ qg, const unsigned short* __restrict__ kg,
    const unsigned short* __restrict__ vg, const int* __restrict__ seq_lens,
    unsigned short* __restrict__ out)
{
    __shared__ unsigned short lds[32768];    // 64 KB: KV double buffer
    const int tid = threadIdx.x;
    const int w = tid >> 6, l = tid & 63;
    const int g4 = (l >> 4) * 4;             // key base of this lane group

    const int bid = blockIdx.x;
    const int qt = bid / (NB * NH);          // 0..15
    const int rem0 = bid - qt * (NB * NH);
    const int h = rem0 >> 1;
    const int b = rem0 & 1;
    const int slen = seq_lens[b];
    const int s0 = qt * QBLK;

    const unsigned short* qbase = qg + ((size_t)(b * NH + h) * SS + s0) * DH;
    const unsigned short* kbase = kg + ((size_t)(b * NH + h) * SS) * DH;
    const unsigned short* vbase = vg + ((size_t)(b * NH + h) * DH) * SS;

    // ---- stage Q (192x128 = 48 KB) through LDS, pull frags to regs ----
    #pragma unroll
    for (int i = 0; i < 12; ++i) {
        int kc = i / 3;
        int r2 = (i % 3) * 256 + tid;        // chunk within kc-slab
        int row = r2 >> 2, sq = r2 & 3;
        GLOAD(qbase + (size_t)row * DH + kc * 32 + (sq ^ ((row >> 1) & 3)) * 8,
              lds + (size_t)(kc * 768 + r2) * 8);
    }
    __syncthreads();
    short8 qf[3][4];
    #pragma unroll
    for (int rb = 0; rb < 3; ++rb)
        #pragma unroll
        for (int kc = 0; kc < 4; ++kc)
            qf[rb][kc] = *(const short8*)&lds[(kc * 768 + swz(w * 48 + rb * 16 + (l & 15), l >> 4)) * 8];
    __syncthreads();   // all waves' Q-frag reads done before region overwrite

    // per-thread chunk descriptors for K/V staging (KVBLK=64)
    int ksrc[4], vsrc[4];
    #pragma unroll
    for (int i = 0; i < 4; ++i) {
        int cid = i * 256 + tid;
        {   int kc = cid >> 8, r2 = cid & 255, row = r2 >> 2, sq = r2 & 3;
            ksrc[i] = row * DH + kc * 32 + (sq ^ ((row >> 1) & 3)) * 8; }
        {   int ks = cid >> 9, r2 = cid & 511, dc = r2 >> 2, sq = r2 & 3;
            vsrc[i] = dc * SS + ks * 32 + (sq ^ ((dc >> 1) & 3)) * 8; }
    }

    const int ntiles = (slen + 63) >> 6;
    const int rem = slen & 63;          // 0 (b=0) or 4 (b=1)

    // prologue: GLOAD tile 0 -> buf0 (K at 0, V at +8192 shorts)
    #pragma unroll
    for (int i = 0; i < 4; ++i) {
        int cid = i * 256 + tid;
        GLOAD(kbase + ksrc[i],        lds + (size_t)cid * 8);
        GLOAD(vbase + vsrc[i],        lds + 8192 + (size_t)cid * 8);
    }

    floatx4 acc[3][8] = {};
    float lsum[3] = {};                 // per-lane: q = l&15 of block rb
    const unsigned short* kpf = kbase + (size_t)64 * DH;   // running prefetch ptrs
    const unsigned short* vpf = vbase + 64;

    // ---- main loop: tiles 0 .. ntiles-2 (all full, no masking) ----
    for (int kt = 0; kt < ntiles - 1; ++kt) {
        __syncthreads();   // drains tile kt's GLOADs (issued a phase ago)

        {   // prefetch tile kt+1 into other buffer
            unsigned short* dst = lds + ((kt + 1) & 1) * 16384;
            #pragma unroll
            for (int i = 0; i < 4; ++i) {
                int cid = i * 256 + tid;
                GLOAD(kpf + ksrc[i], dst + (size_t)cid * 8);
                GLOAD(vpf + vsrc[i], dst + 8192 + (size_t)cid * 8);
            }
            kpf += (size_t)64 * DH;
            vpf += 64;
        }

        const unsigned short* Ks = lds + (kt & 1) * 16384;
        const unsigned short* Vs = Ks + 8192;

        // S^T = K Q^T (swapped): lane holds q=l&15, keys {g4+r + 16*nb}
        floatx4 sv[3][4] = {};
        __builtin_amdgcn_s_setprio(1);
        #pragma unroll
        for (int kc = 0; kc < 4; ++kc) {
            short8 kf[4];
            #pragma unroll
            for (int nb = 0; nb < 4; ++nb)
                kf[nb] = *(const short8*)&Ks[(kc * 256 + swz(nb * 16 + (l & 15), l >> 4)) * 8];
            #pragma unroll
            for (int rb = 0; rb < 3; ++rb)
                #pragma unroll
                for (int nb = 0; nb < 4; ++nb)
                    sv[rb][nb] = __builtin_amdgcn_mfma_f32_16x16x32_bf16(
                        kf[nb], qf[rb][kc], sv[rb][nb], 0, 0, 0);
        }
        __builtin_amdgcn_s_setprio(0);

        // softmax (no max-subtraction, full tile) + in-register P
        short8 pa[3][2];
        #pragma unroll
        for (int rb = 0; rb < 3; ++rb) {
            #pragma unroll
            for (int nb = 0; nb < 4; ++nb)
                #pragma unroll
                for (int r = 0; r < 4; ++r)
                    sv[rb][nb][r] = exp2f(sv[rb][nb][r]);
            #pragma unroll
            for (int nb = 0; nb < 4; ++nb)
                lsum[rb] += (sv[rb][nb][0] + sv[rb][nb][1]) +
                            (sv[rb][nb][2] + sv[rb][nb][3]);

            unsigned dw0[4], dw1[4];
            #pragma unroll
            for (int nb = 0; nb < 4; ++nb) {
                union { __hip_bfloat162 v; unsigned u; } c0, c1;
                c0.v = __float22bfloat162_rn(make_float2(sv[rb][nb][0], sv[rb][nb][1]));
                c1.v = __float22bfloat162_rn(make_float2(sv[rb][nb][2], sv[rb][nb][3]));
                dw0[nb] = c0.u;
                dw1[nb] = c1.u;
            }
            #pragma unroll
            for (int ks = 0; ks < 2; ++ks) {
                unsigned x0 = dw0[2 * ks], y0 = dw0[2 * ks + 1];
                unsigned x1 = dw1[2 * ks], y1 = dw1[2 * ks + 1];
                asm("v_permlane32_swap_b32 %0, %1" : "+v"(x0), "+v"(y0));
                asm("v_permlane16_swap_b32 %0, %1" : "+v"(x0), "+v"(y0));
                asm("v_permlane32_swap_b32 %0, %1" : "+v"(x1), "+v"(y1));
                asm("v_permlane16_swap_b32 %0, %1" : "+v"(x1), "+v"(y1));
                union { short8 s; unsigned u[4]; } pk;
                pk.u[0] = x0; pk.u[1] = x1; pk.u[2] = y0; pk.u[3] = y1;
                pa[rb][ks] = pk.s;
            }
        }

        // O += P V
        __builtin_amdgcn_s_setprio(1);
        #pragma unroll
        for (int ks = 0; ks < 2; ++ks)
            #pragma unroll
            for (int nb2 = 0; nb2 < 8; ++nb2) {
                short8 vf = *(const short8*)&Vs[(ks * 512 + swz(nb2 * 16 + (l & 15), l >> 4)) * 8];
                #pragma unroll
                for (int rb = 0; rb < 3; ++rb)
                    acc[rb][nb2] = __builtin_amdgcn_mfma_f32_16x16x32_bf16(
                        pa[rb][ks], vf, acc[rb][nb2], 0, 0, 0);
            }
        __builtin_amdgcn_s_setprio(0);
    }

    // ---- peeled last tile (kt = ntiles-1): mask only if rem != 0 ----
    {
        const int kt = ntiles - 1;
        __syncthreads();

        const unsigned short* Ks = lds + (kt & 1) * 16384;
        const unsigned short* Vs = Ks + 8192;

        floatx4 sv[3][4] = {};
        __builtin_amdgcn_s_setprio(1);
        #pragma unroll
        for (int kc = 0; kc < 4; ++kc) {
            short8 kf[4];
            #pragma unroll
            for (int nb = 0; nb < 4; ++nb)
                kf[nb] = *(const short8*)&Ks[(kc * 256 + swz(nb * 16 + (l & 15), l >> 4)) * 8];
            #pragma unroll
            for (int rb = 0; rb < 3; ++rb)
                #pragma unroll
                for (int nb = 0; nb < 4; ++nb)
                    sv[rb][nb] = __builtin_amdgcn_mfma_f32_16x16x32_bf16(
                        kf[nb], qf[rb][kc], sv[rb][nb], 0, 0, 0);
        }
        __builtin_amdgcn_s_setprio(0);

        short8 pa[3][2];
        #pragma unroll
        for (int rb = 0; rb < 3; ++rb) {
            if (rem == 0) {
                #pragma unroll
                for (int nb = 0; nb < 4; ++nb)
                    #pragma unroll
                    for (int r = 0; r < 4; ++r)
                        sv[rb][nb][r] = exp2f(sv[rb][nb][r]);
            } else {
                #pragma unroll
                for (int nb = 0; nb < 4; ++nb)
                    #pragma unroll
                    for (int r = 0; r < 4; ++r) {
                        const int key = g4 + r + 16 * nb;
                        sv[rb][nb][r] = (key < rem) ? exp2f(sv[rb][nb][r]) : 0.0f;
                    }
            }
            #pragma unroll
            for (int nb = 0; nb < 4; ++nb)
                lsum[rb] += (sv[rb][nb][0] + sv[rb][nb][1]) +
                            (sv[rb][nb][2] + sv[rb][nb][3]);

            unsigned dw0[4], dw1[4];
            #pragma unroll
            for (int nb = 0; nb < 4; ++nb) {
                union { __hip_bfloat162 v; unsigned u; } c0, c1;
                c0.v = __float22bfloat162_rn(make_float2(sv[rb][nb][0], sv[rb][nb][1]));
                c1.v = __float22bfloat162_rn(make_float2(sv[rb][nb][2], sv[rb][nb][3]));
                dw0[nb] = c0.u;
                dw1[nb] = c1.u;
            }
            #pragma unroll
            for (int ks = 0; ks < 2; ++ks) {
                unsigned x0 = dw0[2 * ks], y0 = dw0[2 * ks + 1];
                unsigned x1 = dw1[2 * ks], y1 = dw1[2 * ks + 1];
                asm("v_permlane32_swap_b32 %0, %1" : "+v"(x0), "+v"(y0));
                asm("v_permlane16_swap_b32 %0, %1" : "+v"(x0), "+v"(y0));
                asm("v_permlane32_swap_b32 %0, %1" : "+v"(x1), "+v"(y1));
                asm("v_permlane16_swap_b32 %0, %1" : "+v"(x1), "+v"(y1));
                union { short8 s; unsigned u[4]; } pk;
                pk.u[0] = x0; pk.u[1] = x1; pk.u[2] = y0; pk.u[3] = y1;
                pa[rb][ks] = pk.s;
            }
        }

        __builtin_amdgcn_s_setprio(1);
        #pragma unroll
        for (int ks = 0; ks < 2; ++ks)
            #pragma unroll
            for (int nb2 = 0; nb2 < 8; ++nb2) {
                short8 vf = *(const short8*)&Vs[(ks * 512 + swz(nb2 * 16 + (l & 15), l >> 4)) * 8];
                #pragma unroll
                for (int rb = 0; rb < 3; ++rb)
                    acc[rb][nb2] = __builtin_amdgcn_mfma_f32_16x16x32_bf16(
                        pa[rb][ks], vf, acc[rb][nb2], 0, 0, 0);
            }
        __builtin_amdgcn_s_setprio(0);
    }

    #pragma unroll
    for (int rb = 0; rb < 3; ++rb) {
        float s = lsum[rb];
        s += __shfl_xor(s, 16, 64);
        s += __shfl_xor(s, 32, 64);
        float rl[4];
        #pragma unroll
        for (int r = 0; r < 4; ++r)
            rl[r] = 1.0f / __shfl(s, g4 + r, 64);
        #pragma unroll
        for (int nb2 = 0; nb2 < 8; ++nb2) {
            const int col = h * DH + nb2 * 16 + (l & 15);
            #pragma unroll
            for (int r = 0; r < 4; ++r) {
                const int srow = s0 + w * 48 + rb * 16 + (l >> 4) * 4 + r;
                out[((size_t)b * SS + srow) * CC + col] = f2bf(acc[rb][nb2][r] * rl[r]);
            }
        }
    }
}

// ---------------------------------------------------------------------------
extern "C" void kernel_launch(void* const* d_in, const int* in_sizes, int n_in,
                              void* d_out, int out_size, void* d_ws, size_t ws_size,
                              hipStream_t stream) {
    const float* x          = (const float*)d_in[0];
    const int*   seq_lens   = (const int*)d_in[1];
    const int*   grid_sizes = (const int*)d_in[2];
    const float* freqs      = (const float*)d_in[3];
    const float* Wq         = (const float*)d_in[4];
    const float* bq         = (const float*)d_in[5];
    const float* Wk         = (const float*)d_in[6];
    const float* bk         = (const float*)d_in[7];
    const float* Wv         = (const float*)d_in[8];
    const float* bv         = (const float*)d_in[9];
    const float* Wo         = (const float*)d_in[10];
    const float* bo         = (const float*)d_in[11];
    const float* nqw        = (const float*)d_in[12];
    const float* nkw        = (const float*)d_in[13];
    float* out = (float*)d_out;

    const size_t TE = (size_t)NTOK * CC;   // 9,437,184 (= 4*WE)
    unsigned short* xb  = (unsigned short*)d_ws;   // xb..wob contiguous
    unsigned short* wqb = xb + TE;
    unsigned short* wkb = wqb + WE;
    unsigned short* wvb = wkb + WE;
    unsigned short* wob = wvb + WE;
    unsigned short* qb  = wob + WE;
    unsigned short* kb  = qb + TE;
    unsigned short* vtb = kb + TE;
    unsigned short* ab  = vtb + TE;
    float2* tab = (float2*)(ab + TE);      // 3072*64 float2 = 1.5 MB

    cast_rope<<<dim3(WE / 1024, 9), 256, 0, stream>>>(
        x, Wq, Wk, Wv, Wo, xb, freqs, grid_sizes, tab);

    qkv_gemm<<<dim3(NTOK / 128, 36), 256, 0, stream>>>(
        xb, wqb, wkb, wvb, bq, bk, bv, qb, kb, vtb);

    norm_rope<<<dim3(NTOK), 256, 0, stream>>>(qb, kb, nqw, nkw, tab);

    flash_attn_mfma<<<dim3(NB * NH * (SS / QBLK)), 256, 0, stream>>>(qb, kb, vtb, seq_lens, ab);

    gemm_o<<<dim3(NTOK / 128, CC / 128), 256, 0, stream>>>(ab, wob, bo, out);
}